// Round 1
// baseline (16986.691 us; speedup 1.0000x reference)
//
#include <hip/hip_runtime.h>
#include <math.h>

#define DIMD 2048
#define NHEAD 16
#define HDIM 128
#define NB 128
#define NR 49
#define NS 100
#define EPSV 1e-5f

constexpr int NIMG = NB * NR;   // 6272 rows
constexpr int NTXT = NB * NS;   // 12800 rows

// ---------------- block-wide reduction of two sums (256 threads = 4 waves) --
__device__ __forceinline__ void block_reduce2(float& a, float& b) {
#pragma unroll
  for (int o = 32; o > 0; o >>= 1) {
    a += __shfl_down(a, o);
    b += __shfl_down(b, o);
  }
  __shared__ float ra[4], rb[4];
  const int w = threadIdx.x >> 6;
  if ((threadIdx.x & 63) == 0) { ra[w] = a; rb[w] = b; }
  __syncthreads();
  a = ra[0] + ra[1] + ra[2] + ra[3];
  b = rb[0] + rb[1] + rb[2] + rb[3];
}

// ---------------- per-row LayerNorm stats: mean + rsqrt(var+eps) ------------
__global__ __launch_bounds__(256) void ln_stats(const float* __restrict__ X,
                                                float* __restrict__ mu,
                                                float* __restrict__ rs) {
  const size_t row = blockIdx.x;
  const float4* xp = reinterpret_cast<const float4*>(X + row * DIMD);
  float s1 = 0.f, s2 = 0.f;
  for (int c = threadIdx.x; c < DIMD / 4; c += 256) {
    float4 v = xp[c];
    s1 += v.x + v.y + v.z + v.w;
    s2 += v.x * v.x + v.y * v.y + v.z * v.z + v.w * v.w;
  }
  block_reduce2(s1, s2);
  if (threadIdx.x == 0) {
    float m = s1 * (1.f / DIMD);
    float var = s2 * (1.f / DIMD) - m * m;
    mu[row] = m;
    rs[row] = rsqrtf(var + EPSV);
  }
}

// ---------------- generic fp32 tiled GEMM: C = op(A) @ W + bias -------------
// AMODE 0: plain A[M,K].  1: LN applied on the fly: (A-mu)*rs*g + b.
//       2: concat along K: A[:,0:KA] then A2[:,0:K-KA].
// EPI   0: none.  1: relu.
// Tile 128x128xBK8, 256 threads, 8x8 per thread (split 4+4 fragments so
// LDS b128 reads are <=2-way bank aliased; 2-way is free on CDNA4).
constexpr int BM = 128, BN = 128, BKK = 8;

template <int AMODE, int EPI>
__global__ __launch_bounds__(256) void gemm_k(
    const float* __restrict__ A, const float* __restrict__ A2,
    const float* __restrict__ mu, const float* __restrict__ rsg,
    const float* __restrict__ lng, const float* __restrict__ lnb,
    const float* __restrict__ W, const float* __restrict__ bias,
    float* __restrict__ C, int M, int N, int K, int KA) {
  __shared__ float As[BKK][BM];
  __shared__ float Bs[BKK][BN];
  const int tid = threadIdx.x;
  const int m0 = blockIdx.y * BM, n0 = blockIdx.x * BN;
  const int am = tid >> 1, ak4 = (tid & 1) * 4;       // A tile: 128 rows x 8 k
  const int bk = tid >> 5, bn4 = (tid & 31) << 2;     // B tile: 8 k x 128 cols
  const int ty = tid >> 4, tx = tid & 15;
  float acc[8][8] = {};
  float lm = 0.f, lr = 0.f;
  if (AMODE == 1) { lm = mu[m0 + am]; lr = rsg[m0 + am]; }
  const int astr = (AMODE == 2) ? KA : K;
  const float* Arow = A + (size_t)(m0 + am) * astr;
  const float* A2row = (AMODE == 2) ? (A2 + (size_t)(m0 + am) * KA) : nullptr;

  for (int k0 = 0; k0 < K; k0 += BKK) {
    const int ka = k0 + ak4;
    float4 av;
    if (AMODE == 2) {
      av = (ka < KA) ? *reinterpret_cast<const float4*>(Arow + ka)
                     : *reinterpret_cast<const float4*>(A2row + (ka - KA));
    } else {
      av = *reinterpret_cast<const float4*>(Arow + ka);
    }
    if (AMODE == 1) {
      av.x = (av.x - lm) * lr * lng[ka + 0] + lnb[ka + 0];
      av.y = (av.y - lm) * lr * lng[ka + 1] + lnb[ka + 1];
      av.z = (av.z - lm) * lr * lng[ka + 2] + lnb[ka + 2];
      av.w = (av.w - lm) * lr * lng[ka + 3] + lnb[ka + 3];
    }
    As[ak4 + 0][am] = av.x;
    As[ak4 + 1][am] = av.y;
    As[ak4 + 2][am] = av.z;
    As[ak4 + 3][am] = av.w;
    *reinterpret_cast<float4*>(&Bs[bk][bn4]) =
        *reinterpret_cast<const float4*>(W + (size_t)(k0 + bk) * N + n0 + bn4);
    __syncthreads();
#pragma unroll
    for (int kk = 0; kk < BKK; ++kk) {
      float ar[8], br[8];
      *reinterpret_cast<float4*>(&ar[0]) = *reinterpret_cast<const float4*>(&As[kk][ty * 4]);
      *reinterpret_cast<float4*>(&ar[4]) = *reinterpret_cast<const float4*>(&As[kk][64 + ty * 4]);
      *reinterpret_cast<float4*>(&br[0]) = *reinterpret_cast<const float4*>(&Bs[kk][tx * 4]);
      *reinterpret_cast<float4*>(&br[4]) = *reinterpret_cast<const float4*>(&Bs[kk][64 + tx * 4]);
#pragma unroll
      for (int i = 0; i < 8; ++i)
#pragma unroll
        for (int j = 0; j < 8; ++j)
          acc[i][j] = fmaf(ar[i], br[j], acc[i][j]);
    }
    __syncthreads();
  }
#pragma unroll
  for (int ih = 0; ih < 2; ++ih)
#pragma unroll
    for (int i = 0; i < 4; ++i) {
      const int m = m0 + ih * 64 + ty * 4 + i;
      float* crow = C + (size_t)m * N;
#pragma unroll
      for (int jh = 0; jh < 2; ++jh) {
        const int n = n0 + jh * 64 + tx * 4;
        float4 v;
        v.x = acc[ih * 4 + i][jh * 4 + 0] + bias[n + 0];
        v.y = acc[ih * 4 + i][jh * 4 + 1] + bias[n + 1];
        v.z = acc[ih * 4 + i][jh * 4 + 2] + bias[n + 2];
        v.w = acc[ih * 4 + i][jh * 4 + 3] + bias[n + 3];
        if (EPI == 1) {
          v.x = fmaxf(v.x, 0.f); v.y = fmaxf(v.y, 0.f);
          v.z = fmaxf(v.z, 0.f); v.w = fmaxf(v.w, 0.f);
        }
        *reinterpret_cast<float4*>(crow + n) = v;
      }
    }
}

// ---------------- fused cross-attention for one (b,h) -----------------------
// scores = (Q K^T)/scale + biasK[key]; softmax over keys; probs -> d_out;
// att = probs @ V. Q/K/V rows live at stride DIMD, head slice h*HDIM.
__global__ __launch_bounds__(256) void attn_cross(
    const float* __restrict__ Q, const float* __restrict__ Km,
    const float* __restrict__ Vm, const float* __restrict__ biasK,
    const float* __restrict__ temp, float* __restrict__ probs,
    float* __restrict__ attout, int nq, int nk) {
  extern __shared__ float sm[];
  float* sQ = sm;                   // nq*128
  float* sKV = sQ + nq * HDIM;      // nk*128 (K, later V)
  float* sS = sKV + nk * HDIM;      // nq*nk
  float* sMx = sS + nq * nk;        // nq
  float* sIs = sMx + nq;            // nq
  const int tid = threadIdx.x;
  const int b = blockIdx.x >> 4, h = blockIdx.x & 15;
  const float invs = 1.f / fmaxf(temp[0], 0.01f);

  const float* qb = Q + ((size_t)b * nq) * DIMD + h * HDIM;
  for (int idx = tid; idx < nq * 32; idx += 256) {
    int r = idx >> 5, c = idx & 31;
    reinterpret_cast<float4*>(sQ)[idx] =
        *reinterpret_cast<const float4*>(qb + (size_t)r * DIMD + c * 4);
  }
  const float* kb = Km + ((size_t)b * nk) * DIMD + h * HDIM;
  for (int idx = tid; idx < nk * 32; idx += 256) {
    int r = idx >> 5, c = idx & 31;
    reinterpret_cast<float4*>(sKV)[idx] =
        *reinterpret_cast<const float4*>(kb + (size_t)r * DIMD + c * 4);
  }
  __syncthreads();
  for (int idx = tid; idx < nq * nk; idx += 256) {
    const int q = idx / nk, s = idx - q * nk;
    const float4* qp = reinterpret_cast<const float4*>(sQ + q * HDIM);
    const float4* kp = reinterpret_cast<const float4*>(sKV + s * HDIM);
    float acc = 0.f;
#pragma unroll
    for (int j = 0; j < 32; ++j) {
      float4 a = qp[j], bb = kp[j];
      acc = fmaf(a.x, bb.x, acc);
      acc = fmaf(a.y, bb.y, acc);
      acc = fmaf(a.z, bb.z, acc);
      acc = fmaf(a.w, bb.w, acc);
    }
    sS[idx] = acc * invs + biasK[s];
  }
  __syncthreads();
  if (tid < nq) {
    float mx = -1e30f;
    for (int s = 0; s < nk; ++s) mx = fmaxf(mx, sS[tid * nk + s]);
    float sum = 0.f;
    for (int s = 0; s < nk; ++s) sum += expf(sS[tid * nk + s] - mx);
    sMx[tid] = mx;
    sIs[tid] = 1.f / sum;
  }
  __syncthreads();
  float* pb = probs + (size_t)blockIdx.x * nq * nk;
  for (int idx = tid; idx < nq * nk; idx += 256) {
    const int q = idx / nk;
    float p = expf(sS[idx] - sMx[q]) * sIs[q];
    sS[idx] = p;
    pb[idx] = p;
  }
  // stage V over K's LDS (K is dead past the scores barrier above)
  const float* vb = Vm + ((size_t)b * nk) * DIMD + h * HDIM;
  for (int idx = tid; idx < nk * 32; idx += 256) {
    int r = idx >> 5, c = idx & 31;
    reinterpret_cast<float4*>(sKV)[idx] =
        *reinterpret_cast<const float4*>(vb + (size_t)r * DIMD + c * 4);
  }
  __syncthreads();
  float* ab = attout + ((size_t)b * nq) * DIMD + h * HDIM;
  for (int idx = tid; idx < nq * 32; idx += 256) {
    const int q = idx >> 5, c4 = idx & 31;
    const float* pr = sS + q * nk;
    const float4* vp = reinterpret_cast<const float4*>(sKV) + c4;
    float4 a = make_float4(0.f, 0.f, 0.f, 0.f);
    for (int s = 0; s < nk; ++s) {
      const float p = pr[s];
      const float4 v = vp[(size_t)s * 32];
      a.x = fmaf(p, v.x, a.x);
      a.y = fmaf(p, v.y, a.y);
      a.z = fmaf(p, v.z, a.z);
      a.w = fmaf(p, v.w, a.w);
    }
    *reinterpret_cast<float4*>(ab + (size_t)q * DIMD + c4 * 4) = a;
  }
}

// ---------------- gate LN + sigmoid + combine: out += sig(LN(G)) * P --------
__global__ __launch_bounds__(256) void gate_combine(
    const float* __restrict__ G, const float* __restrict__ P,
    const float* __restrict__ gg, const float* __restrict__ gb,
    float* __restrict__ out) {
  const size_t row = blockIdx.x;
  const float4* gp = reinterpret_cast<const float4*>(G + row * DIMD);
  const float4* pp = reinterpret_cast<const float4*>(P + row * DIMD);
  float4* op = reinterpret_cast<float4*>(out + row * DIMD);
  float s1 = 0.f, s2 = 0.f;
  float4 loc[2];
#pragma unroll
  for (int i = 0; i < 2; ++i) {
    float4 v = gp[threadIdx.x + i * 256];
    loc[i] = v;
    s1 += v.x + v.y + v.z + v.w;
    s2 += v.x * v.x + v.y * v.y + v.z * v.z + v.w * v.w;
  }
  block_reduce2(s1, s2);
  const float m = s1 * (1.f / DIMD);
  const float r = rsqrtf(s2 * (1.f / DIMD) - m * m + EPSV);
#pragma unroll
  for (int i = 0; i < 2; ++i) {
    const int c = threadIdx.x + i * 256;
    float4 v = loc[i];
    float4 gv = reinterpret_cast<const float4*>(gg)[c];
    float4 bv = reinterpret_cast<const float4*>(gb)[c];
    float4 pv = pp[c];
    float4 o = op[c];
    float y;
    y = (v.x - m) * r * gv.x + bv.x; o.x += pv.x / (1.f + expf(-y));
    y = (v.y - m) * r * gv.y + bv.y; o.y += pv.y / (1.f + expf(-y));
    y = (v.z - m) * r * gv.z + bv.z; o.z += pv.z / (1.f + expf(-y));
    y = (v.w - m) * r * gv.w + bv.w; o.w += pv.w / (1.f + expf(-y));
    op[c] = o;
  }
}

// ---------------- launch ----------------------------------------------------
extern "C" void kernel_launch(void* const* d_in, const int* in_sizes, int n_in,
                              void* d_out, int out_size, void* d_ws, size_t ws_size,
                              hipStream_t stream) {
  (void)in_sizes; (void)n_in; (void)out_size; (void)ws_size;
  const float* img = (const float*)d_in[0];
  const float* txt = (const float*)d_in[1];
  const float* img_q_w = (const float*)d_in[2];
  const float* img_q_b = (const float*)d_in[3];
  const float* img_k_w = (const float*)d_in[4];
  const float* img_k_b = (const float*)d_in[5];
  const float* img_v_w = (const float*)d_in[6];
  const float* img_v_b = (const float*)d_in[7];
  const float* txt_q_w = (const float*)d_in[8];
  const float* txt_q_b = (const float*)d_in[9];
  const float* txt_k_w = (const float*)d_in[10];
  const float* txt_k_b = (const float*)d_in[11];
  const float* txt_v_w = (const float*)d_in[12];
  const float* txt_v_b = (const float*)d_in[13];
  const float* img_out_w = (const float*)d_in[14];
  const float* img_out_b = (const float*)d_in[15];
  const float* txt_out_w = (const float*)d_in[16];
  const float* txt_out_b = (const float*)d_in[17];
  const float* img_res_w = (const float*)d_in[18];
  const float* img_res_b = (const float*)d_in[19];
  const float* txt_res_w = (const float*)d_in[20];
  const float* txt_res_b = (const float*)d_in[21];
  const float* img_gate_w = (const float*)d_in[22];
  const float* img_gate_b = (const float*)d_in[23];
  const float* img_gate_ln_g = (const float*)d_in[24];
  const float* img_gate_ln_b = (const float*)d_in[25];
  const float* txt_gate_w = (const float*)d_in[26];
  const float* txt_gate_b = (const float*)d_in[27];
  const float* txt_gate_ln_g = (const float*)d_in[28];
  const float* txt_gate_ln_b = (const float*)d_in[29];
  const float* img_norm_g = (const float*)d_in[30];
  const float* img_norm_b = (const float*)d_in[31];
  const float* txt_norm_g = (const float*)d_in[32];
  const float* txt_norm_b = (const float*)d_in[33];
  const float* temp = (const float*)d_in[34];
  const float* regb = (const float*)d_in[35];  // [R] (transposed -> key bias)
  const float* tokb = (const float*)d_in[36];  // [S] (key bias)

  // workspace: stats + 3 phased projection slots (~249 MiB total)
  float* ws = (float*)d_ws;
  float* muI = ws;
  float* rsI = muI + NIMG;
  float* muT = rsI + NIMG;
  float* rsT = muT + NTXT;
  float* s1 = rsT + NTXT;                    // img-sized slot (12.8M floats)
  float* s2 = s1 + (size_t)NIMG * DIMD;      // txt-sized slot (26.2M floats)
  float* s3 = s2 + (size_t)NTXT * DIMD;      // txt-sized slot (26.2M floats)

  float* out = (float*)d_out;
  float* enh_img = out;
  float* enh_txt = out + (size_t)NIMG * DIMD;
  float* it_out = enh_txt + (size_t)NTXT * DIMD;
  float* ti_out = it_out + (size_t)NB * NHEAD * NR * NS;
  // d_out enhanced regions double as attention-output scratch; they are
  // overwritten by the residual GEMMs only after their last read.
  float* img_att = enh_img;
  float* txt_att = enh_txt;

  // allow >64KB dynamic LDS for the attention kernel (gfx950 has 160KB/CU)
  hipFuncSetAttribute((const void*)attn_cross,
                      hipFuncAttributeMaxDynamicSharedMemorySize, 160 * 1024);

  ln_stats<<<NIMG, 256, 0, stream>>>(img, muI, rsI);
  ln_stats<<<NTXT, 256, 0, stream>>>(txt, muT, rsT);

  const dim3 gi(DIMD / BN, NIMG / BM);  // 16 x 49
  const dim3 gt(DIMD / BN, NTXT / BM);  // 16 x 100

  // ---- phase 1: iq, tk, tv -> attn img->text (probs it, att -> img_att)
  gemm_k<1, 0><<<gi, 256, 0, stream>>>(img, nullptr, muI, rsI, img_norm_g, img_norm_b,
                                       img_q_w, img_q_b, s1, NIMG, DIMD, DIMD, DIMD);
  gemm_k<1, 0><<<gt, 256, 0, stream>>>(txt, nullptr, muT, rsT, txt_norm_g, txt_norm_b,
                                       txt_k_w, txt_k_b, s2, NTXT, DIMD, DIMD, DIMD);
  gemm_k<1, 0><<<gt, 256, 0, stream>>>(txt, nullptr, muT, rsT, txt_norm_g, txt_norm_b,
                                       txt_v_w, txt_v_b, s3, NTXT, DIMD, DIMD, DIMD);
  const size_t smem1 = (size_t)(NR * HDIM + NS * HDIM + NR * NS + 2 * NR) * sizeof(float);
  attn_cross<<<NB * NHEAD, 256, smem1, stream>>>(s1, s2, s3, tokb, temp, it_out, img_att, NR, NS);

  // ---- phase 2: ik, tq, iv -> attn text->img (probs ti, att -> txt_att)
  gemm_k<1, 0><<<gi, 256, 0, stream>>>(img, nullptr, muI, rsI, img_norm_g, img_norm_b,
                                       img_k_w, img_k_b, s1, NIMG, DIMD, DIMD, DIMD);
  gemm_k<1, 0><<<gt, 256, 0, stream>>>(txt, nullptr, muT, rsT, txt_norm_g, txt_norm_b,
                                       txt_q_w, txt_q_b, s2, NTXT, DIMD, DIMD, DIMD);
  gemm_k<1, 0><<<gi, 256, 0, stream>>>(img, nullptr, muI, rsI, img_norm_g, img_norm_b,
                                       img_v_w, img_v_b, s3, NIMG, DIMD, DIMD, DIMD);
  const size_t smem2 = (size_t)(NS * HDIM + NR * HDIM + NS * NR + 2 * NS) * sizeof(float);
  attn_cross<<<NB * NHEAD, 256, smem2, stream>>>(s2, s1, s3, regb, temp, ti_out, txt_att, NS, NR);

  // ---- img finalize: gate GEMM (concat K=4096), out proj, residual, combine
  gemm_k<2, 0><<<gi, 256, 0, stream>>>(img, img_att, nullptr, nullptr, nullptr, nullptr,
                                       img_gate_w, img_gate_b, s1, NIMG, DIMD, 2 * DIMD, DIMD);
  gemm_k<0, 0><<<gi, 256, 0, stream>>>(img_att, nullptr, nullptr, nullptr, nullptr, nullptr,
                                       img_out_w, img_out_b, s3, NIMG, DIMD, DIMD, DIMD);
  gemm_k<0, 1><<<gi, 256, 0, stream>>>(img, nullptr, nullptr, nullptr, nullptr, nullptr,
                                       img_res_w, img_res_b, enh_img, NIMG, DIMD, DIMD, DIMD);
  gate_combine<<<NIMG, 256, 0, stream>>>(s1, s3, img_gate_ln_g, img_gate_ln_b, enh_img);

  // ---- txt finalize
  gemm_k<2, 0><<<gt, 256, 0, stream>>>(txt, txt_att, nullptr, nullptr, nullptr, nullptr,
                                       txt_gate_w, txt_gate_b, s2, NTXT, DIMD, 2 * DIMD, DIMD);
  gemm_k<0, 0><<<gt, 256, 0, stream>>>(txt_att, nullptr, nullptr, nullptr, nullptr, nullptr,
                                       txt_out_w, txt_out_b, s3, NTXT, DIMD, DIMD, DIMD);
  gemm_k<0, 1><<<gt, 256, 0, stream>>>(txt, nullptr, nullptr, nullptr, nullptr, nullptr,
                                       txt_res_w, txt_res_b, enh_txt, NTXT, DIMD, DIMD, DIMD);
  gate_combine<<<NTXT, 256, 0, stream>>>(s2, s3, txt_gate_ln_g, txt_gate_ln_b, enh_txt);
}

// Round 2
// 6430.665 us; speedup vs baseline: 2.6415x; 2.6415x over previous
//
#include <hip/hip_runtime.h>
#include <math.h>

#define DIMD 2048
#define NHEAD 16
#define HDIM 128
#define NB 128
#define NR 49
#define NS 100
#define EPSV 1e-5f

constexpr int NIMG = NB * NR;   // 6272 rows (49 tiles of 128)
constexpr int NTXT = NB * NS;   // 12800 rows (100 tiles of 128)

typedef _Float16 h8 __attribute__((ext_vector_type(8)));
typedef _Float16 h4 __attribute__((ext_vector_type(4)));
typedef float f4x __attribute__((ext_vector_type(4)));

// async global->LDS, 16B per lane; LDS dest must be wave-uniform base.
#define GLOAD16(g, l)                                             \
  __builtin_amdgcn_global_load_lds(                               \
      (const __attribute__((address_space(1))) void*)(g),         \
      (__attribute__((address_space(3))) void*)(l), 16, 0, 0)

// ---------------- block-wide reduction of two sums (256 thr = 4 waves) ------
__device__ __forceinline__ void block_reduce2(float& a, float& b) {
#pragma unroll
  for (int o = 32; o > 0; o >>= 1) {
    a += __shfl_down(a, o);
    b += __shfl_down(b, o);
  }
  __shared__ float ra[4], rb[4];
  const int w = threadIdx.x >> 6;
  if ((threadIdx.x & 63) == 0) { ra[w] = a; rb[w] = b; }
  __syncthreads();
  a = ra[0] + ra[1] + ra[2] + ra[3];
  b = rb[0] + rb[1] + rb[2] + rb[3];
}

// ---------------- LN + fp16 hi/lo conversion (also raw fp16) ----------------
__global__ __launch_bounds__(256) void ln_convert(
    const float* __restrict__ X, const float* __restrict__ g,
    const float* __restrict__ b, _Float16* __restrict__ Nh,
    _Float16* __restrict__ Nl, _Float16* __restrict__ Rh) {
  const size_t row = blockIdx.x;
  const float4* xp = reinterpret_cast<const float4*>(X + row * DIMD);
  const int t = threadIdx.x;
  float4 v[2];
  float s1 = 0.f, s2 = 0.f;
#pragma unroll
  for (int i = 0; i < 2; ++i) {
    v[i] = xp[t + i * 256];
    s1 += v[i].x + v[i].y + v[i].z + v[i].w;
    s2 += v[i].x * v[i].x + v[i].y * v[i].y + v[i].z * v[i].z + v[i].w * v[i].w;
  }
  block_reduce2(s1, s2);
  const float m = s1 * (1.f / DIMD);
  const float r = rsqrtf(s2 * (1.f / DIMD) - m * m + EPSV);
#pragma unroll
  for (int i = 0; i < 2; ++i) {
    const int c4 = t + i * 256;
    const float4 gv = reinterpret_cast<const float4*>(g)[c4];
    const float4 bv = reinterpret_cast<const float4*>(b)[c4];
    h4 hh, ll, rr;
    float y;
    y = (v[i].x - m) * r * gv.x + bv.x; hh[0] = (_Float16)y; ll[0] = (_Float16)(y - (float)hh[0]); rr[0] = (_Float16)v[i].x;
    y = (v[i].y - m) * r * gv.y + bv.y; hh[1] = (_Float16)y; ll[1] = (_Float16)(y - (float)hh[1]); rr[1] = (_Float16)v[i].y;
    y = (v[i].z - m) * r * gv.z + bv.z; hh[2] = (_Float16)y; ll[2] = (_Float16)(y - (float)hh[2]); rr[2] = (_Float16)v[i].z;
    y = (v[i].w - m) * r * gv.w + bv.w; hh[3] = (_Float16)y; ll[3] = (_Float16)(y - (float)hh[3]); rr[3] = (_Float16)v[i].w;
    reinterpret_cast<h4*>(Nh)[row * (DIMD / 4) + c4] = hh;
    reinterpret_cast<h4*>(Nl)[row * (DIMD / 4) + c4] = ll;
    reinterpret_cast<h4*>(Rh)[row * (DIMD / 4) + c4] = rr;
  }
}

// ---------------- weight transpose + fp16 (hi[/lo]) convert -----------------
// W[K][N] fp32 -> Th/Tl[N][K] fp16.  64x64 tiles via LDS (both sides coalesced)
template <int LO>
__global__ __launch_bounds__(256) void wconv(const float* __restrict__ W,
                                             _Float16* __restrict__ Th,
                                             _Float16* __restrict__ Tl,
                                             int K, int N) {
  __shared__ float tile[64][69];
  const int t = threadIdx.x;
  const int k0 = blockIdx.x * 64, n0 = blockIdx.y * 64;
  const int lr = t >> 4, lc4 = (t & 15) * 4;
#pragma unroll
  for (int i = 0; i < 4; ++i) {
    const int k = lr + i * 16;
    const float4 v = *reinterpret_cast<const float4*>(W + (size_t)(k0 + k) * N + n0 + lc4);
    tile[k][lc4 + 0] = v.x; tile[k][lc4 + 1] = v.y;
    tile[k][lc4 + 2] = v.z; tile[k][lc4 + 3] = v.w;
  }
  __syncthreads();
#pragma unroll
  for (int i = 0; i < 2; ++i) {
    const int c = i * 256 + t;
    const int n = c >> 3, kc = (c & 7) * 8;
    h8 hv, lv;
#pragma unroll
    for (int j = 0; j < 8; ++j) {
      const float f = tile[kc + j][n];
      const _Float16 hh = (_Float16)f;
      hv[j] = hh;
      if (LO) lv[j] = (_Float16)(f - (float)hh);
    }
    *reinterpret_cast<h8*>(Th + (size_t)(n0 + n) * K + k0 + kc) = hv;
    if (LO) *reinterpret_cast<h8*>(Tl + (size_t)(n0 + n) * K + k0 + kc) = lv;
  }
}

// ---------------- fp32 -> fp16 elementwise (8 elems/thread) -----------------
__global__ __launch_bounds__(256) void conv_h(const float* __restrict__ src,
                                              _Float16* __restrict__ dst) {
  const size_t i = ((size_t)blockIdx.x * 256 + threadIdx.x) * 8;
  const float4 a = *reinterpret_cast<const float4*>(src + i);
  const float4 b = *reinterpret_cast<const float4*>(src + i + 4);
  h8 o;
  o[0] = (_Float16)a.x; o[1] = (_Float16)a.y; o[2] = (_Float16)a.z; o[3] = (_Float16)a.w;
  o[4] = (_Float16)b.x; o[5] = (_Float16)b.y; o[6] = (_Float16)b.z; o[7] = (_Float16)b.w;
  *reinterpret_cast<h8*>(dst + i) = o;
}

// ---------------- MFMA fp16 GEMM: C = A @ Bt^T + bias ----------------------
// Bt is [N][K] fp16 (pre-transposed).  128x128x32 tile, 4 waves, each wave a
// 64x64 quadrant via 4x4 fragments of mfma_f32_16x16x32_f16.
// SPLIT==3: C = Ah@Bh + Ah@Bl + Al@Bh  (fp32-grade accuracy via hi/lo split)
// CONCAT:   A is [Ah | A2] along K at KA.   RELU: epilogue max(0,.)
template <int SPLIT, int CONCAT, int RELU>
__global__ __launch_bounds__(256) void mgemm(
    const _Float16* __restrict__ Ah, const _Float16* __restrict__ Al,
    const _Float16* __restrict__ A2,
    const _Float16* __restrict__ Bh, const _Float16* __restrict__ Bl,
    const float* __restrict__ bias, float* __restrict__ C,
    int M, int N, int K, int KA) {
  __shared__ _Float16 sA[(SPLIT == 3 ? 2 : 1) * 128 * 32];
  __shared__ _Float16 sB[(SPLIT == 3 ? 2 : 1) * 128 * 32];
  _Float16* sAh = sA;
  _Float16* sAl = sA + 128 * 32;
  _Float16* sBh = sB;
  _Float16* sBl = sB + 128 * 32;
  const int t = threadIdx.x;
  const int w = t >> 6, l = t & 63;
  const int wr = w >> 1, wc = w & 1;
  const int lm = l & 15, kb4 = l >> 4;
  const int m0 = blockIdx.y * 128, n0 = blockIdx.x * 128;

  f4x acc[4][4] = {};
  const int aBase = kb4 * 128 + wr * 64 + lm;
  const int bBase = kb4 * 128 + wc * 64 + lm;

  for (int k0 = 0; k0 < K; k0 += 32) {
#pragma unroll
    for (int i = 0; i < 2; ++i) {
      const int j = i * 256 + t;        // chunk 0..511
      const int rm = j & 127, kb = j >> 7;
      const int gk = k0 + kb * 8;
      _Float16* const la = sAh + (size_t)(j - l) * 8;  // wave-uniform base
      _Float16* const lb = sBh + (size_t)(j - l) * 8;
      const _Float16* asrc;
      if (CONCAT) {
        asrc = (gk < KA) ? (Ah + (size_t)(m0 + rm) * KA + gk)
                         : (A2 + (size_t)(m0 + rm) * (K - KA) + (gk - KA));
      } else {
        asrc = Ah + (size_t)(m0 + rm) * K + gk;
      }
      GLOAD16(asrc, la);
      GLOAD16(Bh + (size_t)(n0 + rm) * K + gk, lb);
      if constexpr (SPLIT == 3) {
        GLOAD16(Al + (size_t)(m0 + rm) * K + gk, sAl + (size_t)(j - l) * 8);
        GLOAD16(Bl + (size_t)(n0 + rm) * K + gk, sBl + (size_t)(j - l) * 8);
      }
    }
    __syncthreads();
    const h8* pAh = (const h8*)sAh;
    const h8* pBh = (const h8*)sBh;
    h8 fa[4], fb[4];
#pragma unroll
    for (int x = 0; x < 4; ++x) {
      fa[x] = pAh[aBase + x * 16];
      fb[x] = pBh[bBase + x * 16];
    }
    if constexpr (SPLIT == 3) {
      const h8* pAl = (const h8*)sAl;
      const h8* pBl = (const h8*)sBl;
      h8 ga[4], gb[4];
#pragma unroll
      for (int x = 0; x < 4; ++x) {
        ga[x] = pAl[aBase + x * 16];
        gb[x] = pBl[bBase + x * 16];
      }
#pragma unroll
      for (int fm = 0; fm < 4; ++fm)
#pragma unroll
        for (int fn = 0; fn < 4; ++fn) {
          acc[fm][fn] = __builtin_amdgcn_mfma_f32_16x16x32_f16(fa[fm], fb[fn], acc[fm][fn], 0, 0, 0);
          acc[fm][fn] = __builtin_amdgcn_mfma_f32_16x16x32_f16(fa[fm], gb[fn], acc[fm][fn], 0, 0, 0);
          acc[fm][fn] = __builtin_amdgcn_mfma_f32_16x16x32_f16(ga[fm], fb[fn], acc[fm][fn], 0, 0, 0);
        }
    } else {
#pragma unroll
      for (int fm = 0; fm < 4; ++fm)
#pragma unroll
        for (int fn = 0; fn < 4; ++fn)
          acc[fm][fn] = __builtin_amdgcn_mfma_f32_16x16x32_f16(fa[fm], fb[fn], acc[fm][fn], 0, 0, 0);
    }
    __syncthreads();
  }

  float bv[4];
#pragma unroll
  for (int fn = 0; fn < 4; ++fn) bv[fn] = bias[n0 + wc * 64 + fn * 16 + lm];
#pragma unroll
  for (int fm = 0; fm < 4; ++fm) {
    const int rbase = m0 + wr * 64 + fm * 16 + kb4 * 4;
#pragma unroll
    for (int fn = 0; fn < 4; ++fn) {
      const int col = n0 + wc * 64 + fn * 16 + lm;
#pragma unroll
      for (int jj = 0; jj < 4; ++jj) {
        float vv = acc[fm][fn][jj] + bv[fn];
        if (RELU) vv = fmaxf(vv, 0.f);
        C[(size_t)(rbase + jj) * N + col] = vv;
      }
    }
  }
}

// ---------------- fused cross-attention for one (b,h) -----------------------
__global__ __launch_bounds__(256) void attn_cross(
    const float* __restrict__ Q, const float* __restrict__ Km,
    const float* __restrict__ Vm, const float* __restrict__ biasK,
    const float* __restrict__ temp, float* __restrict__ probs,
    float* __restrict__ attout, int nq, int nk) {
  extern __shared__ float sm[];
  float* sQ = sm;
  float* sKV = sQ + nq * HDIM;
  float* sS = sKV + nk * HDIM;
  float* sMx = sS + nq * nk;
  float* sIs = sMx + nq;
  const int tid = threadIdx.x;
  const int b = blockIdx.x >> 4, h = blockIdx.x & 15;
  const float invs = 1.f / fmaxf(temp[0], 0.01f);

  const float* qb = Q + ((size_t)b * nq) * DIMD + h * HDIM;
  for (int idx = tid; idx < nq * 32; idx += 256) {
    int r = idx >> 5, c = idx & 31;
    reinterpret_cast<float4*>(sQ)[idx] =
        *reinterpret_cast<const float4*>(qb + (size_t)r * DIMD + c * 4);
  }
  const float* kb = Km + ((size_t)b * nk) * DIMD + h * HDIM;
  for (int idx = tid; idx < nk * 32; idx += 256) {
    int r = idx >> 5, c = idx & 31;
    reinterpret_cast<float4*>(sKV)[idx] =
        *reinterpret_cast<const float4*>(kb + (size_t)r * DIMD + c * 4);
  }
  __syncthreads();
  for (int idx = tid; idx < nq * nk; idx += 256) {
    const int q = idx / nk, s = idx - q * nk;
    const float4* qp = reinterpret_cast<const float4*>(sQ + q * HDIM);
    const float4* kp = reinterpret_cast<const float4*>(sKV + s * HDIM);
    float acc = 0.f;
#pragma unroll
    for (int j = 0; j < 32; ++j) {
      float4 a = qp[j], bb = kp[j];
      acc = fmaf(a.x, bb.x, acc);
      acc = fmaf(a.y, bb.y, acc);
      acc = fmaf(a.z, bb.z, acc);
      acc = fmaf(a.w, bb.w, acc);
    }
    sS[idx] = acc * invs + biasK[s];
  }
  __syncthreads();
  if (tid < nq) {
    float mx = -1e30f;
    for (int s = 0; s < nk; ++s) mx = fmaxf(mx, sS[tid * nk + s]);
    float sum = 0.f;
    for (int s = 0; s < nk; ++s) sum += expf(sS[tid * nk + s] - mx);
    sMx[tid] = mx;
    sIs[tid] = 1.f / sum;
  }
  __syncthreads();
  float* pb = probs + (size_t)blockIdx.x * nq * nk;
  for (int idx = tid; idx < nq * nk; idx += 256) {
    const int q = idx / nk;
    float p = expf(sS[idx] - sMx[q]) * sIs[q];
    sS[idx] = p;
    pb[idx] = p;
  }
  const float* vb = Vm + ((size_t)b * nk) * DIMD + h * HDIM;
  for (int idx = tid; idx < nk * 32; idx += 256) {
    int r = idx >> 5, c = idx & 31;
    reinterpret_cast<float4*>(sKV)[idx] =
        *reinterpret_cast<const float4*>(vb + (size_t)r * DIMD + c * 4);
  }
  __syncthreads();
  float* ab = attout + ((size_t)b * nq) * DIMD + h * HDIM;
  for (int idx = tid; idx < nq * 32; idx += 256) {
    const int q = idx >> 5, c4 = idx & 31;
    const float* pr = sS + q * nk;
    const float4* vp = reinterpret_cast<const float4*>(sKV) + c4;
    float4 a = make_float4(0.f, 0.f, 0.f, 0.f);
    for (int s = 0; s < nk; ++s) {
      const float p = pr[s];
      const float4 v = vp[(size_t)s * 32];
      a.x = fmaf(p, v.x, a.x);
      a.y = fmaf(p, v.y, a.y);
      a.z = fmaf(p, v.z, a.z);
      a.w = fmaf(p, v.w, a.w);
    }
    *reinterpret_cast<float4*>(ab + (size_t)q * DIMD + c4 * 4) = a;
  }
}

// ---------------- gate LN + sigmoid + combine: out += sig(LN(G)) * P --------
__global__ __launch_bounds__(256) void gate_combine(
    const float* __restrict__ G, const float* __restrict__ P,
    const float* __restrict__ gg, const float* __restrict__ gb,
    float* __restrict__ out) {
  const size_t row = blockIdx.x;
  const float4* gp = reinterpret_cast<const float4*>(G + row * DIMD);
  const float4* pp = reinterpret_cast<const float4*>(P + row * DIMD);
  float4* op = reinterpret_cast<float4*>(out + row * DIMD);
  float s1 = 0.f, s2 = 0.f;
  float4 loc[2];
#pragma unroll
  for (int i = 0; i < 2; ++i) {
    float4 v = gp[threadIdx.x + i * 256];
    loc[i] = v;
    s1 += v.x + v.y + v.z + v.w;
    s2 += v.x * v.x + v.y * v.y + v.z * v.z + v.w * v.w;
  }
  block_reduce2(s1, s2);
  const float m = s1 * (1.f / DIMD);
  const float r = rsqrtf(s2 * (1.f / DIMD) - m * m + EPSV);
#pragma unroll
  for (int i = 0; i < 2; ++i) {
    const int c = threadIdx.x + i * 256;
    float4 v = loc[i];
    float4 gv = reinterpret_cast<const float4*>(gg)[c];
    float4 bv = reinterpret_cast<const float4*>(gb)[c];
    float4 pv = pp[c];
    float4 o = op[c];
    float y;
    y = (v.x - m) * r * gv.x + bv.x; o.x += pv.x / (1.f + expf(-y));
    y = (v.y - m) * r * gv.y + bv.y; o.y += pv.y / (1.f + expf(-y));
    y = (v.z - m) * r * gv.z + bv.z; o.z += pv.z / (1.f + expf(-y));
    y = (v.w - m) * r * gv.w + bv.w; o.w += pv.w / (1.f + expf(-y));
    op[c] = o;
  }
}

// ---------------- launch ----------------------------------------------------
extern "C" void kernel_launch(void* const* d_in, const int* in_sizes, int n_in,
                              void* d_out, int out_size, void* d_ws, size_t ws_size,
                              hipStream_t stream) {
  (void)in_sizes; (void)n_in; (void)out_size; (void)ws_size;
  const float* img = (const float*)d_in[0];
  const float* txt = (const float*)d_in[1];
  const float* img_q_w = (const float*)d_in[2];
  const float* img_q_b = (const float*)d_in[3];
  const float* img_k_w = (const float*)d_in[4];
  const float* img_k_b = (const float*)d_in[5];
  const float* img_v_w = (const float*)d_in[6];
  const float* img_v_b = (const float*)d_in[7];
  const float* txt_q_w = (const float*)d_in[8];
  const float* txt_q_b = (const float*)d_in[9];
  const float* txt_k_w = (const float*)d_in[10];
  const float* txt_k_b = (const float*)d_in[11];
  const float* txt_v_w = (const float*)d_in[12];
  const float* txt_v_b = (const float*)d_in[13];
  const float* img_out_w = (const float*)d_in[14];
  const float* img_out_b = (const float*)d_in[15];
  const float* txt_out_w = (const float*)d_in[16];
  const float* txt_out_b = (const float*)d_in[17];
  const float* img_res_w = (const float*)d_in[18];
  const float* img_res_b = (const float*)d_in[19];
  const float* txt_res_w = (const float*)d_in[20];
  const float* txt_res_b = (const float*)d_in[21];
  const float* img_gate_w = (const float*)d_in[22];
  const float* img_gate_b = (const float*)d_in[23];
  const float* img_gate_ln_g = (const float*)d_in[24];
  const float* img_gate_ln_b = (const float*)d_in[25];
  const float* txt_gate_w = (const float*)d_in[26];
  const float* txt_gate_b = (const float*)d_in[27];
  const float* txt_gate_ln_g = (const float*)d_in[28];
  const float* txt_gate_ln_b = (const float*)d_in[29];
  const float* img_norm_g = (const float*)d_in[30];
  const float* img_norm_b = (const float*)d_in[31];
  const float* txt_norm_g = (const float*)d_in[32];
  const float* txt_norm_b = (const float*)d_in[33];
  const float* temp = (const float*)d_in[34];
  const float* regb = (const float*)d_in[35];
  const float* tokb = (const float*)d_in[36];

  // ---- workspace carve (~647 MB) ----
  char* p = (char*)d_ws;
  auto carve = [&](size_t bytes) {
    char* r = p;
    p += (bytes + 255) & ~(size_t)255;
    return r;
  };
  const size_t szI = (size_t)NIMG * DIMD, szT = (size_t)NTXT * DIMD;
  const size_t szW = (size_t)DIMD * DIMD;
  _Float16* imgN_h = (_Float16*)carve(szI * 2);
  _Float16* imgN_l = (_Float16*)carve(szI * 2);
  _Float16* txtN_h = (_Float16*)carve(szT * 2);
  _Float16* txtN_l = (_Float16*)carve(szT * 2);
  _Float16* img_h  = (_Float16*)carve(szI * 2);
  _Float16* txt_h  = (_Float16*)carve(szT * 2);
  _Float16* WqIh = (_Float16*)carve(szW * 2);
  _Float16* WqIl = (_Float16*)carve(szW * 2);
  _Float16* WkIh = (_Float16*)carve(szW * 2);
  _Float16* WkIl = (_Float16*)carve(szW * 2);
  _Float16* WqTh = (_Float16*)carve(szW * 2);
  _Float16* WqTl = (_Float16*)carve(szW * 2);
  _Float16* WkTh = (_Float16*)carve(szW * 2);
  _Float16* WkTl = (_Float16*)carve(szW * 2);
  _Float16* WvIh = (_Float16*)carve(szW * 2);
  _Float16* WvTh = (_Float16*)carve(szW * 2);
  _Float16* WoIh = (_Float16*)carve(szW * 2);
  _Float16* WoTh = (_Float16*)carve(szW * 2);
  _Float16* WrIh = (_Float16*)carve(szW * 2);
  _Float16* WrTh = (_Float16*)carve(szW * 2);
  _Float16* WgIh = (_Float16*)carve(szW * 4);
  _Float16* WgTh = (_Float16*)carve(szW * 4);
  float* s1 = (float*)carve(szI * 4);   // img-sized fp32
  float* s2 = (float*)carve(szT * 4);   // txt-sized fp32
  float* s3 = (float*)carve(szT * 4);   // txt-sized fp32
  // att fp16 reuses N_l buffers (dead after phase-2 Q/K GEMMs)
  _Float16* attIh = imgN_l;
  _Float16* attTh = txtN_l;

  float* out = (float*)d_out;
  float* enh_img = out;
  float* enh_txt = out + szI;
  float* it_out = enh_txt + szT;
  float* ti_out = it_out + (size_t)NB * NHEAD * NR * NS;
  float* img_att = enh_img;   // fp32 att scratch in d_out (overwritten later)
  float* txt_att = enh_txt;

  hipFuncSetAttribute((const void*)attn_cross,
                      hipFuncAttributeMaxDynamicSharedMemorySize, 160 * 1024);

  // ---- conversions ----
  ln_convert<<<NIMG, 256, 0, stream>>>(img, img_norm_g, img_norm_b, imgN_h, imgN_l, img_h);
  ln_convert<<<NTXT, 256, 0, stream>>>(txt, txt_norm_g, txt_norm_b, txtN_h, txtN_l, txt_h);
  const dim3 wg(DIMD / 64, DIMD / 64);          // 32x32
  const dim3 wgG(2 * DIMD / 64, DIMD / 64);     // 64x32 (gate, K=4096)
  wconv<1><<<wg, 256, 0, stream>>>(img_q_w, WqIh, WqIl, DIMD, DIMD);
  wconv<1><<<wg, 256, 0, stream>>>(img_k_w, WkIh, WkIl, DIMD, DIMD);
  wconv<1><<<wg, 256, 0, stream>>>(txt_q_w, WqTh, WqTl, DIMD, DIMD);
  wconv<1><<<wg, 256, 0, stream>>>(txt_k_w, WkTh, WkTl, DIMD, DIMD);
  wconv<0><<<wg, 256, 0, stream>>>(img_v_w, WvIh, nullptr, DIMD, DIMD);
  wconv<0><<<wg, 256, 0, stream>>>(txt_v_w, WvTh, nullptr, DIMD, DIMD);
  wconv<0><<<wg, 256, 0, stream>>>(img_out_w, WoIh, nullptr, DIMD, DIMD);
  wconv<0><<<wg, 256, 0, stream>>>(txt_out_w, WoTh, nullptr, DIMD, DIMD);
  wconv<0><<<wg, 256, 0, stream>>>(img_res_w, WrIh, nullptr, DIMD, DIMD);
  wconv<0><<<wg, 256, 0, stream>>>(txt_res_w, WrTh, nullptr, DIMD, DIMD);
  wconv<0><<<wgG, 256, 0, stream>>>(img_gate_w, WgIh, nullptr, 2 * DIMD, DIMD);
  wconv<0><<<wgG, 256, 0, stream>>>(txt_gate_w, WgTh, nullptr, 2 * DIMD, DIMD);

  const dim3 gI(DIMD / 128, NIMG / 128);   // 16 x 49
  const dim3 gT(DIMD / 128, NTXT / 128);   // 16 x 100

  // ---- phase 1: iq (split), tk (split), tv -> attn img->text ----
  mgemm<3, 0, 0><<<gI, 256, 0, stream>>>(imgN_h, imgN_l, nullptr, WqIh, WqIl,
                                         img_q_b, s1, NIMG, DIMD, DIMD, 0);
  mgemm<3, 0, 0><<<gT, 256, 0, stream>>>(txtN_h, txtN_l, nullptr, WkTh, WkTl,
                                         txt_k_b, s2, NTXT, DIMD, DIMD, 0);
  mgemm<1, 0, 0><<<gT, 256, 0, stream>>>(txtN_h, nullptr, nullptr, WvTh, nullptr,
                                         txt_v_b, s3, NTXT, DIMD, DIMD, 0);
  const size_t smem1 = (size_t)(NR * HDIM + NS * HDIM + NR * NS + 2 * NR) * sizeof(float);
  attn_cross<<<NB * NHEAD, 256, smem1, stream>>>(s1, s2, s3, tokb, temp, it_out, img_att, NR, NS);

  // ---- phase 2: ik (split), tq (split), iv -> attn text->img ----
  mgemm<3, 0, 0><<<gI, 256, 0, stream>>>(imgN_h, imgN_l, nullptr, WkIh, WkIl,
                                         img_k_b, s1, NIMG, DIMD, DIMD, 0);
  mgemm<3, 0, 0><<<gT, 256, 0, stream>>>(txtN_h, txtN_l, nullptr, WqTh, WqTl,
                                         txt_q_b, s2, NTXT, DIMD, DIMD, 0);
  mgemm<1, 0, 0><<<gI, 256, 0, stream>>>(imgN_h, nullptr, nullptr, WvIh, nullptr,
                                         img_v_b, s3, NIMG, DIMD, DIMD, 0);
  const size_t smem2 = (size_t)(NS * HDIM + NR * HDIM + NS * NR + 2 * NS) * sizeof(float);
  attn_cross<<<NB * NHEAD, 256, smem2, stream>>>(s2, s1, s3, regb, temp, ti_out, txt_att, NS, NR);

  // ---- att fp32 -> fp16 (into dead N_l buffers) ----
  conv_h<<<NIMG, 256, 0, stream>>>(img_att, attIh);
  conv_h<<<NTXT, 256, 0, stream>>>(txt_att, attTh);

  // ---- img finalize ----
  mgemm<1, 1, 0><<<gI, 256, 0, stream>>>(img_h, nullptr, attIh, WgIh, nullptr,
                                         img_gate_b, s1, NIMG, DIMD, 2 * DIMD, DIMD);
  mgemm<1, 0, 0><<<gI, 256, 0, stream>>>(attIh, nullptr, nullptr, WoIh, nullptr,
                                         img_out_b, s2, NIMG, DIMD, DIMD, 0);
  mgemm<1, 0, 1><<<gI, 256, 0, stream>>>(img_h, nullptr, nullptr, WrIh, nullptr,
                                         img_res_b, enh_img, NIMG, DIMD, DIMD, 0);
  gate_combine<<<NIMG, 256, 0, stream>>>(s1, s2, img_gate_ln_g, img_gate_ln_b, enh_img);

  // ---- txt finalize ----
  mgemm<1, 1, 0><<<gT, 256, 0, stream>>>(txt_h, nullptr, attTh, WgTh, nullptr,
                                         txt_gate_b, s3, NTXT, DIMD, 2 * DIMD, DIMD);
  mgemm<1, 0, 0><<<gT, 256, 0, stream>>>(attTh, nullptr, nullptr, WoTh, nullptr,
                                         txt_out_b, s2, NTXT, DIMD, DIMD, 0);
  mgemm<1, 0, 1><<<gT, 256, 0, stream>>>(txt_h, nullptr, nullptr, WrTh, nullptr,
                                         txt_res_b, enh_txt, NTXT, DIMD, DIMD, 0);
  gate_combine<<<NTXT, 256, 0, stream>>>(s3, s2, txt_gate_ln_g, txt_gate_ln_b, enh_txt);
}